// Round 1
// 551.035 us; speedup vs baseline: 1.0433x; 1.0433x over previous
//
#include <hip/hip_runtime.h>
#include <cstdint>
#include <cstddef>

// out = x @ W + (x @ A) @ B ; second output = bias (passthrough)
// Strategy: fold LoRA into the weight (W_eff = W + A@B, transposed bf16),
// cast x to bf16, one big bf16 MFMA GEMM with fp32 accumulate.
// R4: GEMM rewritten as the 256x256 8-phase counted-vmcnt pipeline
// (guide T1+T2+T3+T4+T5). 8 waves/block, BK=64, 128 KiB LDS double-buffer,
// raw s_barrier (no vmcnt drain), vmcnt(2) at phases 1&4 of each K-tile,
// staging runs exactly one K-tile ahead. R3's verified conflict-free
// chunk-XOR LDS swizzle (pos = g ^ (r&7)) retained.
// Workspace: [0,67108864) x_bf16 [8192][4096] ; [67108864,100663296) WeffT.

#define SEQ  8192
#define DIN  4096
#define DOUT 4096
#define RANK 16

typedef __attribute__((ext_vector_type(8))) __bf16 bf16x8;
typedef __attribute__((ext_vector_type(4))) float f32x4;
typedef __attribute__((ext_vector_type(8))) unsigned short ushort8;

#define CAST_BLOCKS ((SEQ * DIN) / (256 * 8))   // 16384
#define WEFF_BLOCKS ((DOUT / 64) * (DIN / 64))  // 4096

__device__ __forceinline__ unsigned short f32_to_bf16_rne(float f) {
  union { float f; unsigned int u; } cv;
  cv.f = f;
  unsigned int u = cv.u;
  u += 0x7FFFu + ((u >> 16) & 1u);
  return (unsigned short)(u >> 16);
}

// ---- Kernel 1 (fused prep): x->bf16 cast + bias copy, and WeffT build ----
__global__ __launch_bounds__(256) void prep_kernel(
    const float* __restrict__ x, unsigned short* __restrict__ xb,
    const float* __restrict__ bias, float* __restrict__ bias_out,
    const float* __restrict__ W, const float* __restrict__ A,
    const float* __restrict__ B, unsigned short* __restrict__ WT) {
  __shared__ float sBf[RANK][64];
  __shared__ float sAf[64][RANK];
  __shared__ unsigned short sT[64][65];   // padded transpose buffer
  const int bid = blockIdx.x;
  const int t = threadIdx.x;

  if (bid < CAST_BLOCKS) {
    const int tid = bid * 256 + t;        // one thread = 8 floats
    const float4* x4 = (const float4*)x;
    float4 v0 = x4[(size_t)tid * 2 + 0];
    float4 v1 = x4[(size_t)tid * 2 + 1];
    ushort8 o;
    o[0] = f32_to_bf16_rne(v0.x); o[1] = f32_to_bf16_rne(v0.y);
    o[2] = f32_to_bf16_rne(v0.z); o[3] = f32_to_bf16_rne(v0.w);
    o[4] = f32_to_bf16_rne(v1.x); o[5] = f32_to_bf16_rne(v1.y);
    o[6] = f32_to_bf16_rne(v1.z); o[7] = f32_to_bf16_rne(v1.w);
    *(ushort8*)(xb + (size_t)tid * 8) = o;
    if (tid < DOUT) bias_out[tid] = bias[tid];
    return;
  }

  // WeffT[n][k] = bf16(W[k][n] + sum_r A[k][r] B[r][n]); 64x64 tile
  const int b  = bid - CAST_BLOCKS;
  const int n0 = (b & 63) * 64;
  const int k0 = (b >> 6) * 64;

  for (int idx = t; idx < RANK * 64; idx += 256) {
    int r = idx >> 6, c = idx & 63;
    sBf[r][c] = B[(size_t)r * DOUT + n0 + c];
  }
  for (int idx = t; idx < 64 * RANK; idx += 256) {
    int i = idx >> 4, r = idx & 15;
    sAf[i][r] = A[(size_t)(k0 + i) * RANK + r];
  }
  __syncthreads();

  const int c   = t & 63;
  const int sub = t >> 6;
  #pragma unroll
  for (int p = 0; p < 16; ++p) {
    const int ki = p * 4 + sub;
    float acc = W[(size_t)(k0 + ki) * DOUT + n0 + c];
    #pragma unroll
    for (int r = 0; r < RANK; ++r) acc += sAf[ki][r] * sBf[r][c];
    sT[ki][c] = f32_to_bf16_rne(acc);
  }
  __syncthreads();
  #pragma unroll
  for (int p = 0; p < 16; ++p) {
    const int ni = p * 4 + sub;
    WT[(size_t)(n0 + ni) * DIN + k0 + c] = sT[c][ni];
  }
}

// ---- Kernel 2: C[m][n] = sum_k xb[m][k] * WT[n][k] ------------------------
// 256x256 tile, BK=64, 512 threads = 8 waves (2 M-bands x 4 N-bands),
// per-wave output 128x64 (8x4 16x16 fragments), 64 MFMA / K-tile / wave.
//
// LDS per operand per buffer: 256 rows x 8 chunks of 16 B (32 KB).
// Chunk g of row r stored at chunk-position p = g ^ (r & 7)  [R3-verified,
// 0 bank conflicts]. Double buffered: 2 x (32+32) KB = 128 KB.
//
// Pipeline (per K-tile tau, buffer p = tau&1; staging targets tau+1, buf p^1):
//   P1: ds a[0..3]@kk0 + b[0..3]@kk0 | stage A-Q0,A-Q2 | vmcnt(2) | bar |
//       lgkm0 | prio1 16xMFMA prio0 | bar
//   P2: ds a[4..7]@kk0               | stage B-Q0,B-Q1 | bar | ... MFMA | bar
//   P3: ds a[0..3]@kk1 + b@kk1       | stage B-Q2,B-Q3 | bar | ... MFMA | bar
//   P4: ds a[4..7]@kk1               | stage A-Q1,A-Q3 | vmcnt(2) | bar | ...
// Quarter Q = 64 rows = one 8 KB global_load_lds slot (512 thr x 16 B).
// Wait-chain (hand-verified incl. prologue and peeled last tile):
//   vmcnt(2) @P4 retires next tile's A-Q0,A-Q2,B-Q0..Q3 (needed at its P1);
//   vmcnt(2) @P1 retires current tile's A-Q1,A-Q3 (needed at its P2).
// In-flight never drains below 2 loads in the main loop (T4).
#define BM 256
#define BN 256
#define BK 64
#define GRID_X (DOUT / BN)    // 16
#define GRID_Y (SEQ / BM)     // 32
#define NWG (GRID_X * GRID_Y) // 512  (multiple of 8 -> simple XCD swizzle OK)

#define BARX()   asm volatile("s_barrier" ::: "memory")
#define LGKM0()  asm volatile("s_waitcnt lgkmcnt(0)" ::: "memory")
#define VM_CNT(n) asm volatile("s_waitcnt vmcnt(" #n ")" ::: "memory")

#define STAGE_A(BUFSEL, Q, KOFF)                                              \
  __builtin_amdgcn_global_load_lds(                                           \
      (const __attribute__((address_space(1))) void*)(gA + (size_t)(Q) * 64 * DIN + (KOFF)), \
      (__attribute__((address_space(3))) void*)(sA + (BUFSEL) * 16384 + (Q) * 4096 + t * 8), \
      16, 0, 0);

#define STAGE_B(BUFSEL, Q, KOFF)                                              \
  __builtin_amdgcn_global_load_lds(                                           \
      (const __attribute__((address_space(1))) void*)(gB + (size_t)(Q) * 64 * DIN + (KOFF)), \
      (__attribute__((address_space(3))) void*)(sB + (BUFSEL) * 16384 + (Q) * 4096 + t * 8), \
      16, 0, 0);

// canonical per-tile stage order: A0,A2, B0,B1, B2,B3, A1,A3
#define STAGE_TILE(BUFSEL, KOFF)                                              \
  STAGE_A(BUFSEL, 0, KOFF); STAGE_A(BUFSEL, 2, KOFF);                         \
  STAGE_B(BUFSEL, 0, KOFF); STAGE_B(BUFSEL, 1, KOFF);                         \
  STAGE_B(BUFSEL, 2, KOFF); STAGE_B(BUFSEL, 3, KOFF);                         \
  STAGE_A(BUFSEL, 1, KOFF); STAGE_A(BUFSEL, 3, KOFF);

#define MFMA16(BASE)                                                          \
  _Pragma("unroll") for (int i_ = 0; i_ < 4; ++i_)                            \
    _Pragma("unroll") for (int j_ = 0; j_ < 4; ++j_)                          \
      acc[(BASE) + i_][j_] = __builtin_amdgcn_mfma_f32_16x16x32_bf16(         \
          a[i_], b[j_], acc[(BASE) + i_][j_], 0, 0, 0);

#define KTILE(ACUR, BCUR, DO_STAGE, NBUF, NKOFF, VMP1)                        \
  {                                                                           \
    bf16x8 a[4], b[4];                                                        \
    /* ---- P1: h=0, kk=0 ---- */                                             \
    _Pragma("unroll") for (int i_ = 0; i_ < 4; ++i_)                          \
      a[i_] = *(const bf16x8*)((ACUR) + aRow + i_ * 1024 + cpos0);            \
    _Pragma("unroll") for (int j_ = 0; j_ < 4; ++j_)                          \
      b[j_] = *(const bf16x8*)((BCUR) + bRow + j_ * 1024 + cpos0);            \
    if (DO_STAGE) { STAGE_A(NBUF, 0, NKOFF); STAGE_A(NBUF, 2, NKOFF); }       \
    VMP1;                                                                     \
    BARX(); LGKM0();                                                          \
    __builtin_amdgcn_s_setprio(1); MFMA16(0); __builtin_amdgcn_s_setprio(0);  \
    BARX();                                                                   \
    /* ---- P2: h=1, kk=0 ---- */                                             \
    _Pragma("unroll") for (int i_ = 0; i_ < 4; ++i_)                          \
      a[i_] = *(const bf16x8*)((ACUR) + aRow + 4096 + i_ * 1024 + cpos0);     \
    if (DO_STAGE) { STAGE_B(NBUF, 0, NKOFF); STAGE_B(NBUF, 1, NKOFF); }       \
    BARX(); LGKM0();                                                          \
    __builtin_amdgcn_s_setprio(1); MFMA16(4); __builtin_amdgcn_s_setprio(0);  \
    BARX();                                                                   \
    /* ---- P3: h=0, kk=1 ---- */                                             \
    _Pragma("unroll") for (int i_ = 0; i_ < 4; ++i_)                          \
      a[i_] = *(const bf16x8*)((ACUR) + aRow + i_ * 1024 + cpos1);            \
    _Pragma("unroll") for (int j_ = 0; j_ < 4; ++j_)                          \
      b[j_] = *(const bf16x8*)((BCUR) + bRow + j_ * 1024 + cpos1);            \
    if (DO_STAGE) { STAGE_B(NBUF, 2, NKOFF); STAGE_B(NBUF, 3, NKOFF); }       \
    BARX(); LGKM0();                                                          \
    __builtin_amdgcn_s_setprio(1); MFMA16(0); __builtin_amdgcn_s_setprio(0);  \
    BARX();                                                                   \
    /* ---- P4: h=1, kk=1 ---- */                                             \
    _Pragma("unroll") for (int i_ = 0; i_ < 4; ++i_)                          \
      a[i_] = *(const bf16x8*)((ACUR) + aRow + 4096 + i_ * 1024 + cpos1);     \
    if (DO_STAGE) { STAGE_A(NBUF, 1, NKOFF); STAGE_A(NBUF, 3, NKOFF); }       \
    VM_CNT(2);                                                                \
    BARX(); LGKM0();                                                          \
    __builtin_amdgcn_s_setprio(1); MFMA16(4); __builtin_amdgcn_s_setprio(0);  \
    BARX();                                                                   \
  }

__global__ __launch_bounds__(512, 2) void gemm_bt_kernel(
    const unsigned short* __restrict__ xb, const unsigned short* __restrict__ wt,
    float* __restrict__ out) {
  __shared__ unsigned short sA[2 * BM * BK];  // 64 KB (two 32 KB buffers)
  __shared__ unsigned short sB[2 * BN * BK];  // 64 KB

  const int t = threadIdx.x;      // 0..511
  const int lane = t & 63;
  const int w    = t >> 6;        // wave 0..7
  const int wr   = w >> 2;        // M band: 128 rows
  const int wc   = w & 3;         // N band: 64 cols
  const int quad = lane >> 4;
  const int lcol = lane & 15;

  // XCD-aware bijective block swizzle (NWG=512, %8==0)
  const int lid = blockIdx.y * GRID_X + blockIdx.x;
  const int swz = (lid & 7) * (NWG / 8) + (lid >> 3);
  const int n0 = (swz & (GRID_X - 1)) * BN;
  const int m0 = (swz / GRID_X) * BM;

  // ---- staging addresses (R3 scheme, 256-row tiles) ----
  // linear 16B slot index l = q*512 + t  -> row r = q*64 + w*8 + (lane>>3),
  // pos = lane&7 ; source chunk g = (lane&7) ^ (lane>>3)  (r&7 == lane>>3 &7)
  const int g    = (lane & 7) ^ (lane >> 3);
  const int srow = w * 8 + (lane >> 3);
  const unsigned short* gA = xb + (size_t)(m0 + srow) * DIN + g * 8;
  const unsigned short* gB = wt + (size_t)(n0 + srow) * DIN + g * 8;

  // ---- fragment read offsets (shorts; row stride 64) ----
  const int xorv  = lcol & 7;
  const int cpos0 = (quad ^ xorv) * 8;        // kk=0 chunk position
  const int cpos1 = cpos0 ^ 32;               // kk=1: chunk+4 -> ^32 shorts
  const int aRow  = (wr * 128 + lcol) * 64;
  const int bRow  = (wc * 64  + lcol) * 64;

  f32x4 acc[8][4] = {};

  // ---- prologue: stage K-tiles 0 (buf0) and 1 (buf1) ----
  STAGE_TILE(0, 0);
  STAGE_TILE(1, 64);
  VM_CNT(8);            // tile 0 fully landed; tile 1's 8 loads in flight
  BARX();

  // ---- tile 0: no staging (tile 1 already issued in prologue) ----
  KTILE(sA, sB, 0, 1, 64, ((void)0));

  // ---- main loop: tiles 1..62, staging tile tau+1 into buffer (tau+1)&1 ----
  #pragma unroll 2
  for (int tau = 1; tau < 63; ++tau) {
    const unsigned short* Ac = sA + (tau & 1) * 16384;
    const unsigned short* Bc = sB + (tau & 1) * 16384;
    const int koff = (tau + 1) * 64;
    KTILE(Ac, Bc, 1, ((tau + 1) & 1), koff, VM_CNT(2));
  }

  // ---- peeled tile 63 (buf1): no staging; drain the last 2 loads at P1 ----
  {
    const unsigned short* Ac = sA + 16384;
    const unsigned short* Bc = sB + 16384;
    KTILE(Ac, Bc, 0, 0, 0, VM_CNT(0));
  }

  // Epilogue: C/D layout col=lane&15, row=(lane>>4)*4+reg [m89/m91]
  #pragma unroll
  for (int f = 0; f < 8; ++f) {
    const int rb = m0 + wr * 128 + (f >> 2) * 64 + (f & 3) * 16 + quad * 4;
    const int cb = n0 + wc * 64 + lcol;
    #pragma unroll
    for (int j = 0; j < 4; ++j)
      #pragma unroll
      for (int r = 0; r < 4; ++r)
        out[(size_t)(rb + r) * DOUT + cb + j * 16] = acc[f][j][r];
  }
}

extern "C" void kernel_launch(void* const* d_in, const int* in_sizes, int n_in,
                              void* d_out, int out_size, void* d_ws, size_t ws_size,
                              hipStream_t stream) {
  const float* x    = (const float*)d_in[0];
  const float* W    = (const float*)d_in[1];
  const float* bias = (const float*)d_in[2];
  const float* A    = (const float*)d_in[3];
  const float* B    = (const float*)d_in[4];
  float* out      = (float*)d_out;
  float* bias_out = out + (size_t)SEQ * DOUT;

  unsigned short* xb = (unsigned short*)d_ws;
  unsigned short* wt = xb + (size_t)SEQ * DIN;

  prep_kernel<<<CAST_BLOCKS + WEFF_BLOCKS, 256, 0, stream>>>(
      x, xb, bias, bias_out, W, A, B, wt);
  gemm_bt_kernel<<<dim3(GRID_X, GRID_Y), 512, 0, stream>>>(xb, wt, out);
}

// Round 2
// 518.271 us; speedup vs baseline: 1.1092x; 1.0632x over previous
//
#include <hip/hip_runtime.h>
#include <cstdint>
#include <cstddef>

// out = x @ W + (x @ A) @ B ; second output = bias (passthrough)
// Strategy: fold LoRA into the weight (W_eff = W + A@B, transposed bf16),
// cast x to bf16, one big bf16 MFMA GEMM with fp32 accumulate.
// R5: (a) GEMM: half-granular freed-region staging. Each 256-row LDS operand
//     is two 128-row halves; waves take fragments from BOTH halves
//     (interleaved row/col mapping), phases = C-quadrants:
//       Ph1: (Ah0 x Bh0) reads a0-3(2kk)+b01(2kk)=12, stage Ah1(t+1)->other buf
//       Ph2: (Ah0 x Bh1) reads b23=4,               stage Bh0(t+2)->cur buf
//       Ph3: (Ah1 x Bh1) reads a4-7=8,              stage Ah0(t+2)
//       Ph4: (Ah1 x Bh0) reads 0 (b01 kept in regs), stage Bh1(t+2)
//     Every staged load now has >=6 phases of slack; steady waits are
//     vmcnt(10) at end of Ph1/Ph2/Ph4 (none at Ph3) -> in-flight never
//     below 10 (true T4; R4 drained to 2 twice per tile).
//     Ledger verified by hand: prologue vmcnt(12); tile62 waits 10/8/6;
//     tile63 waits 2/0. Chunk-XOR conflict-free LDS swizzle retained.
// (b) prep split into cast_kernel + weff_kernel (observability) and weff
//     LDS traffic cut 3.4x: B-column in 16 regs, A rows read as float4,
//     ushort8 final stores.
// Workspace: [0,67108864) x_bf16 [8192][4096] ; [67108864,100663296) WeffT.

#define SEQ  8192
#define DIN  4096
#define DOUT 4096
#define RANK 16

typedef __attribute__((ext_vector_type(8))) __bf16 bf16x8;
typedef __attribute__((ext_vector_type(4))) float f32x4;
typedef __attribute__((ext_vector_type(8))) unsigned short ushort8;

#define CAST_BLOCKS ((SEQ * DIN) / (256 * 8))   // 16384
#define WEFF_BLOCKS ((DOUT / 64) * (DIN / 64))  // 4096

__device__ __forceinline__ unsigned short f32_to_bf16_rne(float f) {
  union { float f; unsigned int u; } cv;
  cv.f = f;
  unsigned int u = cv.u;
  u += 0x7FFFu + ((u >> 16) & 1u);
  return (unsigned short)(u >> 16);
}

// ---- Kernel 1a: x->bf16 cast + bias copy --------------------------------
__global__ __launch_bounds__(256) void cast_kernel(
    const float* __restrict__ x, unsigned short* __restrict__ xb,
    const float* __restrict__ bias, float* __restrict__ bias_out) {
  const int tid = blockIdx.x * 256 + threadIdx.x;   // one thread = 8 floats
  const float4* x4 = (const float4*)x;
  float4 v0 = x4[(size_t)tid * 2 + 0];
  float4 v1 = x4[(size_t)tid * 2 + 1];
  ushort8 o;
  o[0] = f32_to_bf16_rne(v0.x); o[1] = f32_to_bf16_rne(v0.y);
  o[2] = f32_to_bf16_rne(v0.z); o[3] = f32_to_bf16_rne(v0.w);
  o[4] = f32_to_bf16_rne(v1.x); o[5] = f32_to_bf16_rne(v1.y);
  o[6] = f32_to_bf16_rne(v1.z); o[7] = f32_to_bf16_rne(v1.w);
  *(ushort8*)(xb + (size_t)tid * 8) = o;
  if (tid < DOUT) bias_out[tid] = bias[tid];
}

// ---- Kernel 1b: WeffT[n][k] = bf16(W[k][n] + sum_r A[k][r] B[r][n]) ------
// 64x64 tile per block. B column kept in registers (16 b32 reads/thread),
// A rows read as float4 (4 b128/row), 16-B final stores via padded sT.
__global__ __launch_bounds__(256) void weff_kernel(
    const float* __restrict__ W, const float* __restrict__ A,
    const float* __restrict__ B, unsigned short* __restrict__ WT) {
  __shared__ float sBf[RANK][64];        // 4 KB
  __shared__ float sAf[64][16];          // 4 KB, rows = 64 B (float4-able)
  __shared__ unsigned short sT[64][65];  // padded transpose buffer
  const int blk = blockIdx.x;
  const int n0 = (blk & 63) * 64;
  const int k0 = (blk >> 6) * 64;
  const int t = threadIdx.x;

  #pragma unroll
  for (int pass = 0; pass < 4; ++pass) {
    const int idx = pass * 256 + t;      // 0..1023
    sBf[idx >> 6][idx & 63] = B[(size_t)(idx >> 6) * DOUT + n0 + (idx & 63)];
    sAf[idx >> 4][idx & 15] = A[(size_t)(k0 + (idx >> 4)) * RANK + (idx & 15)];
  }
  __syncthreads();

  const int c   = t & 63;
  const int sub = t >> 6;
  float breg[16];
  #pragma unroll
  for (int r = 0; r < 16; ++r) breg[r] = sBf[r][c];   // conflict-free (64 consecutive c)

  #pragma unroll
  for (int p = 0; p < 16; ++p) {
    const int ki = p * 4 + sub;
    const float4* ar = (const float4*)sAf[ki];        // wave-uniform -> broadcast
    const float4 a0 = ar[0], a1 = ar[1], a2 = ar[2], a3 = ar[3];
    float acc = W[(size_t)(k0 + ki) * DOUT + n0 + c];
    acc += a0.x * breg[0]  + a0.y * breg[1]  + a0.z * breg[2]  + a0.w * breg[3];
    acc += a1.x * breg[4]  + a1.y * breg[5]  + a1.z * breg[6]  + a1.w * breg[7];
    acc += a2.x * breg[8]  + a2.y * breg[9]  + a2.z * breg[10] + a2.w * breg[11];
    acc += a3.x * breg[12] + a3.y * breg[13] + a3.z * breg[14] + a3.w * breg[15];
    sT[ki][c] = f32_to_bf16_rne(acc);
  }
  __syncthreads();

  #pragma unroll
  for (int s = 0; s < 2; ++s) {
    const int ni = (t >> 3) + s * 32;
    const int cc = t & 7;
    ushort8 o;
    #pragma unroll
    for (int u = 0; u < 8; ++u) o[u] = sT[cc * 8 + u][ni];
    *(ushort8*)(WT + (size_t)(n0 + ni) * DIN + k0 + cc * 8) = o;
  }
}

// ---- Kernel 2: C[m][n] = sum_k xb[m][k] * WT[n][k] ------------------------
// 256x256 tile, BK=64, 512 threads = 8 waves (2M x 4N), per-wave C 128x64.
// Wave fragment mapping interleaves tile halves:
//   A-frag i (0..7): row = (i>>2)*128 + wr*64 + (i&3)*16 + lcol
//   B-frag j (0..3): col = (j>>1)*128 + wc*32 + (j&1)*16 + lcol
// LDS: per operand per buffer 256 rows x 8 chunks of 16 B (32 KB); chunk g of
// row r at position g ^ (r&7) (conflict-free, R3/R4-verified). 128 KB total.
#define BM 256
#define BN 256
#define BK 64
#define GRID_X (DOUT / BN)    // 16
#define GRID_Y (SEQ / BM)     // 32
#define NWG (GRID_X * GRID_Y) // 512  (multiple of 8 -> XCD swizzle exact)

#define BARX()   asm volatile("s_barrier" ::: "memory")
#define LGKM(n)  asm volatile("s_waitcnt lgkmcnt(" #n ")" ::: "memory")
#define VMW(n)   asm volatile("s_waitcnt vmcnt(" #n ")" ::: "memory")

// Stage one 128-row half (2 x global_load_lds of 8 KB) of A or B.
// Dest is wave-uniform base + lane*16 (t*8 shorts). Source chunk g and row
// srow are precomputed per-thread so that LDS pos = g ^ (row&7) holds.
#define STAGE_AH(BUF, H, KOFF)                                                 \
  __builtin_amdgcn_global_load_lds(                                            \
      (const __attribute__((address_space(1))) void*)(gA + (size_t)((H)*128 + 0)  * DIN + (KOFF)),  \
      (__attribute__((address_space(3))) void*)(sA + (BUF)*16384 + (H)*8192 + 0    + t*8), 16, 0, 0);\
  __builtin_amdgcn_global_load_lds(                                            \
      (const __attribute__((address_space(1))) void*)(gA + (size_t)((H)*128 + 64) * DIN + (KOFF)),  \
      (__attribute__((address_space(3))) void*)(sA + (BUF)*16384 + (H)*8192 + 4096 + t*8), 16, 0, 0);

#define STAGE_BH(BUF, H, KOFF)                                                 \
  __builtin_amdgcn_global_load_lds(                                            \
      (const __attribute__((address_space(1))) void*)(gB + (size_t)((H)*128 + 0)  * DIN + (KOFF)),  \
      (__attribute__((address_space(3))) void*)(sB + (BUF)*16384 + (H)*8192 + 0    + t*8), 16, 0, 0);\
  __builtin_amdgcn_global_load_lds(                                            \
      (const __attribute__((address_space(1))) void*)(gB + (size_t)((H)*128 + 64) * DIN + (KOFF)),  \
      (__attribute__((address_space(3))) void*)(sB + (BUF)*16384 + (H)*8192 + 4096 + t*8), 16, 0, 0);

#define MFMA(A, B, C) __builtin_amdgcn_mfma_f32_16x16x32_bf16(A, B, C, 0, 0, 0)

// One K-tile. CUR = buffer index (runtime 0/1). KOFF1/KOFF2 = short offsets
// of tiles t+1 / t+2. S1/S234 enable Ph1 / Ph2-4 staging. W1/W2/W4 = vmcnt
// literals at end of Ph1/Ph2/Ph4 (ledger-derived; Ph3 needs none).
#define KTILE(CUR, KOFF1, KOFF2, S1, S234, W1, W2, W4)                         \
  {                                                                            \
    const int ab_ = (CUR) * 16384;                                             \
    const int bb_ = (CUR) * 16384;                                             \
    bf16x8 a[4][2], b01[2][2], b23[2][2];                                      \
    /* ---- Ph1: (Ah0 x Bh0), 12 reads ---- */                                 \
    _Pragma("unroll") for (int i = 0; i < 4; ++i) {                            \
      a[i][0] = *(const bf16x8*)(sA + ab_ + aoff[i] + cp0);                    \
      a[i][1] = *(const bf16x8*)(sA + ab_ + aoff[i] + cp1); }                  \
    _Pragma("unroll") for (int j = 0; j < 2; ++j) {                            \
      b01[j][0] = *(const bf16x8*)(sB + bb_ + boff[j] + cp0);                  \
      b01[j][1] = *(const bf16x8*)(sB + bb_ + boff[j] + cp1); }                \
    if (S1) { STAGE_AH((CUR) ^ 1, 1, KOFF1); }                                 \
    LGKM(8);                                                                   \
    BARX(); LGKM(0);                                                           \
    __builtin_amdgcn_s_setprio(1);                                             \
    _Pragma("unroll") for (int i = 0; i < 4; ++i)                              \
      _Pragma("unroll") for (int j = 0; j < 2; ++j) {                          \
        acc[i][j] = MFMA(a[i][0], b01[j][0], acc[i][j]);                       \
        acc[i][j] = MFMA(a[i][1], b01[j][1], acc[i][j]); }                     \
    __builtin_amdgcn_s_setprio(0);                                             \
    VMW(W1); BARX();                                                           \
    /* ---- Ph2: (Ah0 x Bh1), 4 reads ---- */                                  \
    _Pragma("unroll") for (int j = 0; j < 2; ++j) {                            \
      b23[j][0] = *(const bf16x8*)(sB + bb_ + boff[j + 2] + cp0);              \
      b23[j][1] = *(const bf16x8*)(sB + bb_ + boff[j + 2] + cp1); }            \
    if (S234) { STAGE_BH((CUR), 0, KOFF2); }                                   \
    BARX(); LGKM(0);                                                           \
    __builtin_amdgcn_s_setprio(1);                                             \
    _Pragma("unroll") for (int i = 0; i < 4; ++i)                              \
      _Pragma("unroll") for (int j = 0; j < 2; ++j) {                          \
        acc[i][j + 2] = MFMA(a[i][0], b23[j][0], acc[i][j + 2]);               \
        acc[i][j + 2] = MFMA(a[i][1], b23[j][1], acc[i][j + 2]); }             \
    __builtin_amdgcn_s_setprio(0);                                             \
    VMW(W2); BARX();                                                           \
    /* ---- Ph3: (Ah1 x Bh1), 8 reads ---- */                                  \
    _Pragma("unroll") for (int i = 0; i < 4; ++i) {                            \
      a[i][0] = *(const bf16x8*)(sA + ab_ + aoff[i + 4] + cp0);                \
      a[i][1] = *(const bf16x8*)(sA + ab_ + aoff[i + 4] + cp1); }              \
    if (S234) { STAGE_AH((CUR), 0, KOFF2); }                                   \
    BARX(); LGKM(0);                                                           \
    __builtin_amdgcn_s_setprio(1);                                             \
    _Pragma("unroll") for (int i = 0; i < 4; ++i)                              \
      _Pragma("unroll") for (int j = 0; j < 2; ++j) {                          \
        acc[i + 4][j + 2] = MFMA(a[i][0], b23[j][0], acc[i + 4][j + 2]);       \
        acc[i + 4][j + 2] = MFMA(a[i][1], b23[j][1], acc[i + 4][j + 2]); }     \
    __builtin_amdgcn_s_setprio(0);                                             \
    BARX();                                                                    \
    /* ---- Ph4: (Ah1 x Bh0), 0 reads (a from Ph3, b01 from Ph1) ---- */       \
    if (S234) { STAGE_BH((CUR), 1, KOFF2); }                                   \
    __builtin_amdgcn_s_setprio(1);                                             \
    _Pragma("unroll") for (int i = 0; i < 4; ++i)                              \
      _Pragma("unroll") for (int j = 0; j < 2; ++j) {                          \
        acc[i + 4][j] = MFMA(a[i][0], b01[j][0], acc[i + 4][j]);               \
        acc[i + 4][j] = MFMA(a[i][1], b01[j][1], acc[i + 4][j]); }             \
    __builtin_amdgcn_s_setprio(0);                                             \
    VMW(W4); BARX();                                                           \
  }

__global__ __launch_bounds__(512, 2) void gemm_bt_kernel(
    const unsigned short* __restrict__ xb, const unsigned short* __restrict__ wt,
    float* __restrict__ out) {
  __shared__ unsigned short sA[2 * BM * BK];  // 64 KB (two 32 KB buffers)
  __shared__ unsigned short sB[2 * BN * BK];  // 64 KB

  const int t = threadIdx.x;      // 0..511
  const int lane = t & 63;
  const int w    = t >> 6;        // wave 0..7
  const int wr   = w >> 2;        // M band select (interleaved halves)
  const int wc   = w & 3;         // N band select
  const int quad = lane >> 4;
  const int lcol = lane & 15;

  // XCD-aware bijective block swizzle (NWG=512, %8==0)
  const int lid = blockIdx.y * GRID_X + blockIdx.x;
  const int swz = (lid & 7) * (NWG / 8) + (lid >> 3);
  const int n0 = (swz & (GRID_X - 1)) * BN;
  const int m0 = (swz / GRID_X) * BM;

  // ---- staging addresses ----
  const int g    = (lane & 7) ^ (lane >> 3);  // source chunk
  const int srow = w * 8 + (lane >> 3);       // row within each 64-row load
  const unsigned short* gA = xb + (size_t)(m0 + srow) * DIN + g * 8;
  const unsigned short* gB = wt + (size_t)(n0 + srow) * DIN + g * 8;

  // ---- fragment read offsets (shorts; row stride 64) ----
  const int xorv = lcol & 7;
  const int cp0  = (quad ^ xorv) * 8;         // kk=0 chunk position
  const int cp1  = cp0 ^ 32;                  // kk=1 (chunk+4)
  int aoff[8], boff[4];
  #pragma unroll
  for (int i = 0; i < 8; ++i)
    aoff[i] = ((i >> 2) * 128 + wr * 64 + (i & 3) * 16 + lcol) * 64;
  #pragma unroll
  for (int j = 0; j < 4; ++j)
    boff[j] = ((j >> 1) * 128 + wc * 32 + (j & 1) * 16 + lcol) * 64;

  f32x4 acc[8][4] = {};

  // ---- prologue: tiles 0 (buf0) and 1 (buf1), consumption order ----
  STAGE_AH(0, 0, 0);  STAGE_BH(0, 0, 0);  STAGE_BH(0, 1, 0);  STAGE_AH(0, 1, 0);
  STAGE_AH(1, 0, 64); STAGE_BH(1, 0, 64); STAGE_BH(1, 1, 64); STAGE_AH(1, 1, 64);
  VMW(12);            // tile0 Ah0+Bh0 (loads 1-4) landed
  BARX();

  // tile 0: Ah1(1) already staged in prologue -> S1=0
  KTILE(0, 64, 128, 0, 1, 10, 10, 10);

  // tiles 1..61 steady: Ph1 stages Ah1(t+1), Ph2-4 stage tile t+2
  #pragma unroll 2
  for (int tt = 1; tt < 62; ++tt) {
    const int cur = tt & 1;
    const int koff1 = (tt + 1) * BK;
    const int koff2 = (tt + 2) * BK;
    KTILE(cur, koff1, koff2, 1, 1, 10, 10, 10);
  }

  // tile 62 (buf0): stage only Ah1(63); tightened waits (ledger)
  KTILE(0, 63 * BK, 0, 1, 0, 10, 8, 6);
  // tile 63 (buf1): no staging; drain (2 then 0)
  KTILE(1, 0, 0, 0, 0, 2, 0, 0);

  // Epilogue: C/D layout col=lane&15, row=(lane>>4)*4+reg [m89/m91],
  // with the interleaved-half fragment mapping.
  #pragma unroll
  for (int i = 0; i < 8; ++i) {
    const int rb = m0 + (i >> 2) * 128 + wr * 64 + (i & 3) * 16 + quad * 4;
    #pragma unroll
    for (int j = 0; j < 4; ++j) {
      const int cb = n0 + (j >> 1) * 128 + wc * 32 + (j & 1) * 16 + lcol;
      #pragma unroll
      for (int r = 0; r < 4; ++r)
        out[(size_t)(rb + r) * DOUT + cb] = acc[i][j][r];
    }
  }
}

extern "C" void kernel_launch(void* const* d_in, const int* in_sizes, int n_in,
                              void* d_out, int out_size, void* d_ws, size_t ws_size,
                              hipStream_t stream) {
  const float* x    = (const float*)d_in[0];
  const float* W    = (const float*)d_in[1];
  const float* bias = (const float*)d_in[2];
  const float* A    = (const float*)d_in[3];
  const float* B    = (const float*)d_in[4];
  float* out      = (float*)d_out;
  float* bias_out = out + (size_t)SEQ * DOUT;

  unsigned short* xb = (unsigned short*)d_ws;
  unsigned short* wt = xb + (size_t)SEQ * DIN;

  cast_kernel<<<CAST_BLOCKS, 256, 0, stream>>>(x, xb, bias, bias_out);
  weff_kernel<<<WEFF_BLOCKS, 256, 0, stream>>>(W, A, B, wt);
  gemm_bt_kernel<<<dim3(GRID_X, GRID_Y), 512, 0, stream>>>(xb, wt, out);
}

// Round 3
// 510.172 us; speedup vs baseline: 1.1268x; 1.0159x over previous
//
#include <hip/hip_runtime.h>
#include <cstdint>
#include <cstddef>

// out = x @ W + (x @ A) @ B ; second output = bias (passthrough)
// Strategy: fold LoRA into the weight (W_eff = W + A@B, transposed bf16),
// cast x to bf16, one big bf16 MFMA GEMM with fp32 accumulate.
// R6: SINGLE barrier per phase (4/tile instead of 8). Legal because every
// staging target is now freed >=2 phases before its stage-issue
// (stage schedule Ph1/Ph3/Ph3/Ph4), which makes the one-barrier-per-phase
// write-after-read chain provably safe:
//   fast wave's stage-issue@s > BAR(s-1) > slow wave's read-complete@s-2.
// vmcnt ledger (re-derived, forced-retirement-only simulation):
//   prologue: 14 loads, vmcnt(10), bar
//   steady tiles 0..61: phase-end waits (Ph1,Ph2,Ph3,Ph4) = (10, 8, -, 10)
//     Ph1-end 10 guards Ph2's b23; Ph2-end 8 guards Ph3's a4-7;
//     Ph4-end 10 guards next tile's Ph1 (retires loads >=6 phases old).
//   tile 62: (10, 8, -, 4) ; tile 63: (2, 0, -, -).
// In-flight never below 6; waits+barrier pairs collectively guard staged
// data (vmcnt is per-wave; the following s_barrier makes it block-wide).
// Dropped LGKM(0)/LGKM(8) asm: compiler emits fine-grained lgkmcnt(N).
// Chunk-XOR conflict-free LDS swizzle retained (0 conflicts measured).
// Workspace: [0,67108864) x_bf16 [8192][4096] ; [67108864,100663296) WeffT.

#define SEQ  8192
#define DIN  4096
#define DOUT 4096
#define RANK 16

typedef __attribute__((ext_vector_type(8))) __bf16 bf16x8;
typedef __attribute__((ext_vector_type(4))) float f32x4;
typedef __attribute__((ext_vector_type(8))) unsigned short ushort8;

#define CAST_BLOCKS ((SEQ * DIN) / (256 * 8))   // 16384
#define WEFF_BLOCKS ((DOUT / 64) * (DIN / 64))  // 4096

__device__ __forceinline__ unsigned short f32_to_bf16_rne(float f) {
  union { float f; unsigned int u; } cv;
  cv.f = f;
  unsigned int u = cv.u;
  u += 0x7FFFu + ((u >> 16) & 1u);
  return (unsigned short)(u >> 16);
}

// ---- Kernel 1a: x->bf16 cast + bias copy --------------------------------
__global__ __launch_bounds__(256) void cast_kernel(
    const float* __restrict__ x, unsigned short* __restrict__ xb,
    const float* __restrict__ bias, float* __restrict__ bias_out) {
  const int tid = blockIdx.x * 256 + threadIdx.x;   // one thread = 8 floats
  const float4* x4 = (const float4*)x;
  float4 v0 = x4[(size_t)tid * 2 + 0];
  float4 v1 = x4[(size_t)tid * 2 + 1];
  ushort8 o;
  o[0] = f32_to_bf16_rne(v0.x); o[1] = f32_to_bf16_rne(v0.y);
  o[2] = f32_to_bf16_rne(v0.z); o[3] = f32_to_bf16_rne(v0.w);
  o[4] = f32_to_bf16_rne(v1.x); o[5] = f32_to_bf16_rne(v1.y);
  o[6] = f32_to_bf16_rne(v1.z); o[7] = f32_to_bf16_rne(v1.w);
  *(ushort8*)(xb + (size_t)tid * 8) = o;
  if (tid < DOUT) bias_out[tid] = bias[tid];
}

// ---- Kernel 1b: WeffT[n][k] = bf16(W[k][n] + sum_r A[k][r] B[r][n]) ------
__global__ __launch_bounds__(256) void weff_kernel(
    const float* __restrict__ W, const float* __restrict__ A,
    const float* __restrict__ B, unsigned short* __restrict__ WT) {
  __shared__ float sBf[RANK][64];        // 4 KB
  __shared__ float sAf[64][16];          // 4 KB
  __shared__ unsigned short sT[64][65];  // padded transpose buffer
  const int blk = blockIdx.x;
  const int n0 = (blk & 63) * 64;
  const int k0 = (blk >> 6) * 64;
  const int t = threadIdx.x;

  #pragma unroll
  for (int pass = 0; pass < 4; ++pass) {
    const int idx = pass * 256 + t;      // 0..1023
    sBf[idx >> 6][idx & 63] = B[(size_t)(idx >> 6) * DOUT + n0 + (idx & 63)];
    sAf[idx >> 4][idx & 15] = A[(size_t)(k0 + (idx >> 4)) * RANK + (idx & 15)];
  }
  __syncthreads();

  const int c   = t & 63;
  const int sub = t >> 6;
  float breg[16];
  #pragma unroll
  for (int r = 0; r < 16; ++r) breg[r] = sBf[r][c];

  #pragma unroll
  for (int p = 0; p < 16; ++p) {
    const int ki = p * 4 + sub;
    const float4* ar = (const float4*)sAf[ki];        // wave-uniform -> broadcast
    const float4 a0 = ar[0], a1 = ar[1], a2 = ar[2], a3 = ar[3];
    float acc = W[(size_t)(k0 + ki) * DOUT + n0 + c];
    acc += a0.x * breg[0]  + a0.y * breg[1]  + a0.z * breg[2]  + a0.w * breg[3];
    acc += a1.x * breg[4]  + a1.y * breg[5]  + a1.z * breg[6]  + a1.w * breg[7];
    acc += a2.x * breg[8]  + a2.y * breg[9]  + a2.z * breg[10] + a2.w * breg[11];
    acc += a3.x * breg[12] + a3.y * breg[13] + a3.z * breg[14] + a3.w * breg[15];
    sT[ki][c] = f32_to_bf16_rne(acc);
  }
  __syncthreads();

  #pragma unroll
  for (int s = 0; s < 2; ++s) {
    const int ni = (t >> 3) + s * 32;
    const int cc = t & 7;
    ushort8 o;
    #pragma unroll
    for (int u = 0; u < 8; ++u) o[u] = sT[cc * 8 + u][ni];
    *(ushort8*)(WT + (size_t)(n0 + ni) * DIN + k0 + cc * 8) = o;
  }
}

// ---- Kernel 2: C[m][n] = sum_k xb[m][k] * WT[n][k] ------------------------
// 256x256 tile, BK=64, 512 threads = 8 waves (2M x 4N), per-wave C 128x64.
// Fragment mapping interleaves tile halves:
//   A-frag i (0..7): row = (i>>2)*128 + wr*64 + (i&3)*16 + lcol
//   B-frag j (0..3): col = (j>>1)*128 + wc*32 + (j&1)*16 + lcol
// LDS: per operand per buffer 256 rows x 8 chunks of 16 B (32 KB); chunk g of
// row r at position g ^ (r&7) (conflict-free, verified). 128 KB total.
//
// Per-tile phases (ONE barrier each):
//   Ph1: read a0-3(2kk)+b01(2kk)=12 | stage Ah1(t+1)->buf^1 | vmw | BAR | MFMA q00
//   Ph2: read b23=4                 | (no stage)            | vmw | BAR | MFMA q01
//   Ph3: read a4-7=8                | stage Bh0,Ah0(t+2)->cur |   | BAR | MFMA q11
//   Ph4: (no reads; regs)           | stage Bh1(t+2)->cur   | vmw | BAR | MFMA q10
// Freed->staged gaps: buf^1.Ah1 read Ph3(t-1) staged Ph1(t) = 2 phases;
// cur.Bh0/Ah0 read Ph1 staged Ph3 = 2; cur.Bh1 read Ph2 staged Ph4 = 2.
#define BM 256
#define BN 256
#define BK 64
#define GRID_X (DOUT / BN)    // 16
#define GRID_Y (SEQ / BM)     // 32
#define NWG (GRID_X * GRID_Y) // 512

#define BARX()   asm volatile("s_barrier" ::: "memory")
#define VMW(n)   asm volatile("s_waitcnt vmcnt(" #n ")" ::: "memory")

#define STAGE_AH(BUF, H, KOFF)                                                 \
  __builtin_amdgcn_global_load_lds(                                            \
      (const __attribute__((address_space(1))) void*)(gA + (size_t)((H)*128 + 0)  * DIN + (KOFF)),  \
      (__attribute__((address_space(3))) void*)(sA + (BUF)*16384 + (H)*8192 + 0    + t*8), 16, 0, 0);\
  __builtin_amdgcn_global_load_lds(                                            \
      (const __attribute__((address_space(1))) void*)(gA + (size_t)((H)*128 + 64) * DIN + (KOFF)),  \
      (__attribute__((address_space(3))) void*)(sA + (BUF)*16384 + (H)*8192 + 4096 + t*8), 16, 0, 0);

#define STAGE_BH(BUF, H, KOFF)                                                 \
  __builtin_amdgcn_global_load_lds(                                            \
      (const __attribute__((address_space(1))) void*)(gB + (size_t)((H)*128 + 0)  * DIN + (KOFF)),  \
      (__attribute__((address_space(3))) void*)(sB + (BUF)*16384 + (H)*8192 + 0    + t*8), 16, 0, 0);\
  __builtin_amdgcn_global_load_lds(                                            \
      (const __attribute__((address_space(1))) void*)(gB + (size_t)((H)*128 + 64) * DIN + (KOFF)),  \
      (__attribute__((address_space(3))) void*)(sB + (BUF)*16384 + (H)*8192 + 4096 + t*8), 16, 0, 0);

#define MFMA(A, B, C) __builtin_amdgcn_mfma_f32_16x16x32_bf16(A, B, C, 0, 0, 0)

// One K-tile, 4 phases, ONE s_barrier per phase. W1/W2/W4 are the phase-end
// vmcnt waits (statements), placed BEFORE the barrier so that wait+barrier
// collectively guarantees all waves' staged loads retired before the next
// phase's ds_reads issue.
#define KTILE(CUR, KOFF1, KOFF2, S1, S34, W1, W2, W4)                          \
  {                                                                            \
    const int ab_ = (CUR) * 16384;                                             \
    bf16x8 a[4][2], b01[2][2], b23[2][2];                                      \
    /* ---- Ph1 ---- */                                                        \
    _Pragma("unroll") for (int i = 0; i < 4; ++i) {                            \
      a[i][0] = *(const bf16x8*)(sA + ab_ + aoff[i] + cp0);                    \
      a[i][1] = *(const bf16x8*)(sA + ab_ + aoff[i] + cp1); }                  \
    _Pragma("unroll") for (int j = 0; j < 2; ++j) {                            \
      b01[j][0] = *(const bf16x8*)(sB + ab_ + boff[j] + cp0);                  \
      b01[j][1] = *(const bf16x8*)(sB + ab_ + boff[j] + cp1); }                \
    if (S1) { STAGE_AH((CUR) ^ 1, 1, KOFF1); }                                 \
    W1; BARX();                                                                \
    __builtin_amdgcn_s_setprio(1);                                             \
    _Pragma("unroll") for (int i = 0; i < 4; ++i)                              \
      _Pragma("unroll") for (int j = 0; j < 2; ++j) {                          \
        acc[i][j] = MFMA(a[i][0], b01[j][0], acc[i][j]);                       \
        acc[i][j] = MFMA(a[i][1], b01[j][1], acc[i][j]); }                     \
    __builtin_amdgcn_s_setprio(0);                                             \
    /* ---- Ph2 ---- */                                                        \
    _Pragma("unroll") for (int j = 0; j < 2; ++j) {                            \
      b23[j][0] = *(const bf16x8*)(sB + ab_ + boff[j + 2] + cp0);              \
      b23[j][1] = *(const bf16x8*)(sB + ab_ + boff[j + 2] + cp1); }            \
    W2; BARX();                                                                \
    __builtin_amdgcn_s_setprio(1);                                             \
    _Pragma("unroll") for (int i = 0; i < 4; ++i)                              \
      _Pragma("unroll") for (int j = 0; j < 2; ++j) {                          \
        acc[i][j + 2] = MFMA(a[i][0], b23[j][0], acc[i][j + 2]);               \
        acc[i][j + 2] = MFMA(a[i][1], b23[j][1], acc[i][j + 2]); }             \
    __builtin_amdgcn_s_setprio(0);                                             \
    /* ---- Ph3 ---- */                                                        \
    _Pragma("unroll") for (int i = 0; i < 4; ++i) {                            \
      a[i][0] = *(const bf16x8*)(sA + ab_ + aoff[i + 4] + cp0);                \
      a[i][1] = *(const bf16x8*)(sA + ab_ + aoff[i + 4] + cp1); }              \
    if (S34) { STAGE_BH((CUR), 0, KOFF2); STAGE_AH((CUR), 0, KOFF2); }         \
    BARX();                                                                    \
    __builtin_amdgcn_s_setprio(1);                                             \
    _Pragma("unroll") for (int i = 0; i < 4; ++i)                              \
      _Pragma("unroll") for (int j = 0; j < 2; ++j) {                          \
        acc[i + 4][j + 2] = MFMA(a[i][0], b23[j][0], acc[i + 4][j + 2]);       \
        acc[i + 4][j + 2] = MFMA(a[i][1], b23[j][1], acc[i + 4][j + 2]); }     \
    __builtin_amdgcn_s_setprio(0);                                             \
    /* ---- Ph4 (no ds_reads; a from Ph3, b01 from Ph1) ---- */                \
    if (S34) { STAGE_BH((CUR), 1, KOFF2); }                                    \
    W4; BARX();                                                                \
    __builtin_amdgcn_s_setprio(1);                                             \
    _Pragma("unroll") for (int i = 0; i < 4; ++i)                              \
      _Pragma("unroll") for (int j = 0; j < 2; ++j) {                          \
        acc[i + 4][j] = MFMA(a[i][0], b01[j][0], acc[i + 4][j]);               \
        acc[i + 4][j] = MFMA(a[i][1], b01[j][1], acc[i + 4][j]); }             \
    __builtin_amdgcn_s_setprio(0);                                             \
  }

__global__ __launch_bounds__(512, 2) void gemm_bt_kernel(
    const unsigned short* __restrict__ xb, const unsigned short* __restrict__ wt,
    float* __restrict__ out) {
  __shared__ unsigned short sA[2 * BM * BK];  // 64 KB
  __shared__ unsigned short sB[2 * BN * BK];  // 64 KB

  const int t = threadIdx.x;      // 0..511
  const int lane = t & 63;
  const int w    = t >> 6;        // wave 0..7
  const int wr   = w >> 2;
  const int wc   = w & 3;
  const int quad = lane >> 4;
  const int lcol = lane & 15;

  // XCD-aware bijective block swizzle (NWG=512, %8==0)
  const int lid = blockIdx.y * GRID_X + blockIdx.x;
  const int swz = (lid & 7) * (NWG / 8) + (lid >> 3);
  const int n0 = (swz & (GRID_X - 1)) * BN;
  const int m0 = (swz / GRID_X) * BM;

  // ---- staging addresses ----
  const int g    = (lane & 7) ^ (lane >> 3);  // source chunk
  const int srow = w * 8 + (lane >> 3);
  const unsigned short* gA = xb + (size_t)(m0 + srow) * DIN + g * 8;
  const unsigned short* gB = wt + (size_t)(n0 + srow) * DIN + g * 8;

  // ---- fragment read offsets (shorts; row stride 64) ----
  const int xorv = lcol & 7;
  const int cp0  = (quad ^ xorv) * 8;
  const int cp1  = cp0 ^ 32;
  int aoff[8], boff[4];
  #pragma unroll
  for (int i = 0; i < 8; ++i)
    aoff[i] = ((i >> 2) * 128 + wr * 64 + (i & 3) * 16 + lcol) * 64;
  #pragma unroll
  for (int j = 0; j < 4; ++j)
    boff[j] = ((j >> 1) * 128 + wc * 32 + (j & 1) * 16 + lcol) * 64;

  f32x4 acc[8][4] = {};

  // ---- prologue: queue order = steady-state consumption order ----
  // [Bh0(0),Ah0(0),Bh1(0),Ah1(0),Bh0(1),Ah0(1),Bh1(1)] = 14 loads
  STAGE_BH(0, 0, 0);  STAGE_AH(0, 0, 0);  STAGE_BH(0, 1, 0);  STAGE_AH(0, 1, 0);
  STAGE_BH(1, 0, 64); STAGE_AH(1, 0, 64); STAGE_BH(1, 1, 64);
  VMW(10);            // retires Bh0(0)+Ah0(0) for tile0 Ph1
  BARX();

  // tiles 0..61: fully steady (Ph1 stages Ah1(t+1); Ph3/4 stage t+2)
  #pragma unroll 2
  for (int tt = 0; tt < 62; ++tt) {
    const int cur = tt & 1;
    KTILE(cur, (tt + 1) * BK, (tt + 2) * BK, 1, 1, VMW(10), VMW(8), VMW(10));
  }
  // tile 62 (buf0): stage only Ah1(63); tail waits per ledger
  KTILE(0, 63 * BK, 0, 1, 0, VMW(10), VMW(8), VMW(4));
  // tile 63 (buf1): no staging; drain
  KTILE(1, 0, 0, 0, 0, VMW(2), VMW(0), ((void)0));

  // Epilogue: C/D layout col=lane&15, row=(lane>>4)*4+reg [m89/m91]
  #pragma unroll
  for (int i = 0; i < 8; ++i) {
    const int rb = m0 + (i >> 2) * 128 + wr * 64 + (i & 3) * 16 + quad * 4;
    #pragma unroll
    for (int j = 0; j < 4; ++j) {
      const int cb = n0 + (j >> 1) * 128 + wc * 32 + (j & 1) * 16 + lcol;
      #pragma unroll
      for (int r = 0; r < 4; ++r)
        out[(size_t)(rb + r) * DOUT + cb] = acc[i][j][r];
    }
  }
}

extern "C" void kernel_launch(void* const* d_in, const int* in_sizes, int n_in,
                              void* d_out, int out_size, void* d_ws, size_t ws_size,
                              hipStream_t stream) {
  const float* x    = (const float*)d_in[0];
  const float* W    = (const float*)d_in[1];
  const float* bias = (const float*)d_in[2];
  const float* A    = (const float*)d_in[3];
  const float* B    = (const float*)d_in[4];
  float* out      = (float*)d_out;
  float* bias_out = out + (size_t)SEQ * DOUT;

  unsigned short* xb = (unsigned short*)d_ws;
  unsigned short* wt = xb + (size_t)SEQ * DIN;

  cast_kernel<<<CAST_BLOCKS, 256, 0, stream>>>(x, xb, bias, bias_out);
  weff_kernel<<<WEFF_BLOCKS, 256, 0, stream>>>(W, A, B, wt);
  gemm_bt_kernel<<<dim3(GRID_X, GRID_Y), 512, 0, stream>>>(xb, wt, out);
}

// Round 4
// 502.303 us; speedup vs baseline: 1.1445x; 1.0157x over previous
//
#include <hip/hip_runtime.h>
#include <cstdint>
#include <cstddef>

// out = x @ W + (x @ A) @ B ; second output = bias (passthrough)
// Strategy: fold LoRA into the weight (W_eff = W + A@B, transposed bf16),
// cast x to bf16, one big bf16 MFMA GEMM with fp32 accumulate.
// R7: TWO barriers per K-tile (mid + end). The kernel is LDS-read-pipe
// bound (192 ds_read_b128/tile/CU ~= 2800 cyc wall vs 620 MFMA); fewer
// barriers let reads of one wave overlap MFMA of the other wave across
// 2-phase spans. Hazard proof (airtight, ordering-based):
//   WAR: every staged region's final ds_reads are consumed by an MFMA
//     (lgkmcnt-forced completion) BEFORE a barrier that PRECEDES the
//     stage-issue:
//       Ph1 stage Ah1(t+1)->buf^1 : region read in tile t-1 Ph3, consumed
//         by q11 before t-1's END-BAR  < stage-issue in tile t Ph1.
//       Ph3 stage Bh0/Ah0(t+2)->cur: read Ph1, consumed by q00/q01
//         before MID-BAR < stage-issue after MID-BAR.
//       Ph4 stage Bh1(t+2)->cur   : read Ph2, consumed by q01 before
//         MID-BAR < stage-issue after MID-BAR.
//   RAW: single publish point. vmcnt(6)+END-BAR retires (per-wave FIFO:
//     6 in-flight + 2+4+2 staged - retire 8) exactly ALL of tile t+1's
//     loads. Prologue 14 loads -> vmw(6); tile62 -> vmw(0); tile63 none.
// Prep re-merged into one dispatch (R3 residual 237 vs R6 split 256).
// Chunk-XOR conflict-free LDS swizzle retained (0 conflicts measured).
// Workspace: [0,67108864) x_bf16 [8192][4096] ; [67108864,100663296) WeffT.

#define SEQ  8192
#define DIN  4096
#define DOUT 4096
#define RANK 16

typedef __attribute__((ext_vector_type(8))) __bf16 bf16x8;
typedef __attribute__((ext_vector_type(4))) float f32x4;
typedef __attribute__((ext_vector_type(8))) unsigned short ushort8;

#define CAST_BLOCKS ((SEQ * DIN) / (256 * 8))   // 16384
#define WEFF_BLOCKS ((DOUT / 64) * (DIN / 64))  // 4096

__device__ __forceinline__ unsigned short f32_to_bf16_rne(float f) {
  union { float f; unsigned int u; } cv;
  cv.f = f;
  unsigned int u = cv.u;
  u += 0x7FFFu + ((u >> 16) & 1u);
  return (unsigned short)(u >> 16);
}

// ---- Kernel 1 (fused prep): x->bf16 cast + bias copy, and WeffT build ----
__global__ __launch_bounds__(256) void prep_kernel(
    const float* __restrict__ x, unsigned short* __restrict__ xb,
    const float* __restrict__ bias, float* __restrict__ bias_out,
    const float* __restrict__ W, const float* __restrict__ A,
    const float* __restrict__ B, unsigned short* __restrict__ WT) {
  __shared__ float sBf[RANK][64];        // 4 KB
  __shared__ float sAf[64][16];          // 4 KB
  __shared__ unsigned short sT[64][65];  // padded transpose buffer
  const int bid = blockIdx.x;
  const int t = threadIdx.x;

  if (bid < CAST_BLOCKS) {
    const int tid = bid * 256 + t;        // one thread = 8 floats
    const float4* x4 = (const float4*)x;
    float4 v0 = x4[(size_t)tid * 2 + 0];
    float4 v1 = x4[(size_t)tid * 2 + 1];
    ushort8 o;
    o[0] = f32_to_bf16_rne(v0.x); o[1] = f32_to_bf16_rne(v0.y);
    o[2] = f32_to_bf16_rne(v0.z); o[3] = f32_to_bf16_rne(v0.w);
    o[4] = f32_to_bf16_rne(v1.x); o[5] = f32_to_bf16_rne(v1.y);
    o[6] = f32_to_bf16_rne(v1.z); o[7] = f32_to_bf16_rne(v1.w);
    *(ushort8*)(xb + (size_t)tid * 8) = o;
    if (tid < DOUT) bias_out[tid] = bias[tid];
    return;
  }

  // WeffT[n][k] = bf16(W[k][n] + sum_r A[k][r] B[r][n]); 64x64 tile
  const int blk = bid - CAST_BLOCKS;
  const int n0 = (blk & 63) * 64;
  const int k0 = (blk >> 6) * 64;

  #pragma unroll
  for (int pass = 0; pass < 4; ++pass) {
    const int idx = pass * 256 + t;      // 0..1023
    sBf[idx >> 6][idx & 63] = B[(size_t)(idx >> 6) * DOUT + n0 + (idx & 63)];
    sAf[idx >> 4][idx & 15] = A[(size_t)(k0 + (idx >> 4)) * RANK + (idx & 15)];
  }
  __syncthreads();

  const int c   = t & 63;
  const int sub = t >> 6;
  float breg[16];
  #pragma unroll
  for (int r = 0; r < 16; ++r) breg[r] = sBf[r][c];

  #pragma unroll
  for (int p = 0; p < 16; ++p) {
    const int ki = p * 4 + sub;
    const float4* ar = (const float4*)sAf[ki];        // wave-uniform -> broadcast
    const float4 a0 = ar[0], a1 = ar[1], a2 = ar[2], a3 = ar[3];
    float acc = W[(size_t)(k0 + ki) * DOUT + n0 + c];
    acc += a0.x * breg[0]  + a0.y * breg[1]  + a0.z * breg[2]  + a0.w * breg[3];
    acc += a1.x * breg[4]  + a1.y * breg[5]  + a1.z * breg[6]  + a1.w * breg[7];
    acc += a2.x * breg[8]  + a2.y * breg[9]  + a2.z * breg[10] + a2.w * breg[11];
    acc += a3.x * breg[12] + a3.y * breg[13] + a3.z * breg[14] + a3.w * breg[15];
    sT[ki][c] = f32_to_bf16_rne(acc);
  }
  __syncthreads();

  #pragma unroll
  for (int s = 0; s < 2; ++s) {
    const int ni = (t >> 3) + s * 32;
    const int cc = t & 7;
    ushort8 o;
    #pragma unroll
    for (int u = 0; u < 8; ++u) o[u] = sT[cc * 8 + u][ni];
    *(ushort8*)(WT + (size_t)(n0 + ni) * DIN + k0 + cc * 8) = o;
  }
}

// ---- Kernel 2: C[m][n] = sum_k xb[m][k] * WT[n][k] ------------------------
// 256x256 tile, BK=64, 512 threads = 8 waves (2M x 4N), per-wave C 128x64.
// Fragment mapping interleaves tile halves:
//   A-frag i (0..7): row = (i>>2)*128 + wr*64 + (i&3)*16 + lcol
//   B-frag j (0..3): col = (j>>1)*128 + wc*32 + (j&1)*16 + lcol
// LDS: per operand per buffer 256 rows x 8 chunks of 16 B (32 KB); chunk g of
// row r at position g ^ (r&7) (conflict-free, verified). 128 KB total.
//
// Per-tile structure (TWO barriers):
//   Ph1: read a0-3,b01 (12) | stage Ah1(t+1)->buf^1 | MFMA q00
//   Ph2: read b23 (4)       |                       | MFMA q01
//   MID-BAR
//   Ph3: read a4-7 (8)      | stage Bh0,Ah0(t+2)->cur | MFMA q11
//   Ph4: (regs only)        | stage Bh1(t+2)->cur     | MFMA q10
//   vmcnt(6) ; END-BAR      (publishes ALL of tile t+1)
#define BM 256
#define BN 256
#define BK 64
#define GRID_X (DOUT / BN)    // 16
#define GRID_Y (SEQ / BM)     // 32
#define NWG (GRID_X * GRID_Y) // 512

#define BARX()   asm volatile("s_barrier" ::: "memory")
#define VMW(n)   asm volatile("s_waitcnt vmcnt(" #n ")" ::: "memory")

#define STAGE_AH(BUF, H, KOFF)                                                 \
  __builtin_amdgcn_global_load_lds(                                            \
      (const __attribute__((address_space(1))) void*)(gA + (size_t)((H)*128 + 0)  * DIN + (KOFF)),  \
      (__attribute__((address_space(3))) void*)(sA + (BUF)*16384 + (H)*8192 + 0    + t*8), 16, 0, 0);\
  __builtin_amdgcn_global_load_lds(                                            \
      (const __attribute__((address_space(1))) void*)(gA + (size_t)((H)*128 + 64) * DIN + (KOFF)),  \
      (__attribute__((address_space(3))) void*)(sA + (BUF)*16384 + (H)*8192 + 4096 + t*8), 16, 0, 0);

#define STAGE_BH(BUF, H, KOFF)                                                 \
  __builtin_amdgcn_global_load_lds(                                            \
      (const __attribute__((address_space(1))) void*)(gB + (size_t)((H)*128 + 0)  * DIN + (KOFF)),  \
      (__attribute__((address_space(3))) void*)(sB + (BUF)*16384 + (H)*8192 + 0    + t*8), 16, 0, 0);\
  __builtin_amdgcn_global_load_lds(                                            \
      (const __attribute__((address_space(1))) void*)(gB + (size_t)((H)*128 + 64) * DIN + (KOFF)),  \
      (__attribute__((address_space(3))) void*)(sB + (BUF)*16384 + (H)*8192 + 4096 + t*8), 16, 0, 0);

#define MFMA(A, B, C) __builtin_amdgcn_mfma_f32_16x16x32_bf16(A, B, C, 0, 0, 0)

// One K-tile, TWO s_barriers. ENDW = tile-end vmcnt statement.
#define KTILE(CUR, KOFF1, KOFF2, S1, S34, ENDW)                                \
  {                                                                            \
    const int ab_ = (CUR) * 16384;                                             \
    bf16x8 a[4][2], b01[2][2], b23[2][2];                                      \
    /* ---- Ph1 ---- */                                                        \
    _Pragma("unroll") for (int i = 0; i < 4; ++i) {                            \
      a[i][0] = *(const bf16x8*)(sA + ab_ + aoff[i] + cp0);                    \
      a[i][1] = *(const bf16x8*)(sA + ab_ + aoff[i] + cp1); }                  \
    _Pragma("unroll") for (int j = 0; j < 2; ++j) {                            \
      b01[j][0] = *(const bf16x8*)(sB + ab_ + boff[j] + cp0);                  \
      b01[j][1] = *(const bf16x8*)(sB + ab_ + boff[j] + cp1); }                \
    if (S1) { STAGE_AH((CUR) ^ 1, 1, KOFF1); }                                 \
    __builtin_amdgcn_s_setprio(1);                                             \
    _Pragma("unroll") for (int i = 0; i < 4; ++i)                              \
      _Pragma("unroll") for (int j = 0; j < 2; ++j) {                          \
        acc[i][j] = MFMA(a[i][0], b01[j][0], acc[i][j]);                       \
        acc[i][j] = MFMA(a[i][1], b01[j][1], acc[i][j]); }                     \
    __builtin_amdgcn_s_setprio(0);                                             \
    /* ---- Ph2 ---- */                                                        \
    _Pragma("unroll") for (int j = 0; j < 2; ++j) {                            \
      b23[j][0] = *(const bf16x8*)(sB + ab_ + boff[j + 2] + cp0);              \
      b23[j][1] = *(const bf16x8*)(sB + ab_ + boff[j + 2] + cp1); }            \
    __builtin_amdgcn_s_setprio(1);                                             \
    _Pragma("unroll") for (int i = 0; i < 4; ++i)                              \
      _Pragma("unroll") for (int j = 0; j < 2; ++j) {                          \
        acc[i][j + 2] = MFMA(a[i][0], b23[j][0], acc[i][j + 2]);               \
        acc[i][j + 2] = MFMA(a[i][1], b23[j][1], acc[i][j + 2]); }             \
    __builtin_amdgcn_s_setprio(0);                                             \
    BARX();  /* MID: publishes nothing; orders Ph1/Ph2 reads vs Ph3/Ph4 stages */ \
    /* ---- Ph3 ---- */                                                        \
    _Pragma("unroll") for (int i = 0; i < 4; ++i) {                            \
      a[i][0] = *(const bf16x8*)(sA + ab_ + aoff[i + 4] + cp0);                \
      a[i][1] = *(const bf16x8*)(sA + ab_ + aoff[i + 4] + cp1); }              \
    if (S34) { STAGE_BH((CUR), 0, KOFF2); STAGE_AH((CUR), 0, KOFF2); }         \
    __builtin_amdgcn_s_setprio(1);                                             \
    _Pragma("unroll") for (int i = 0; i < 4; ++i)                              \
      _Pragma("unroll") for (int j = 0; j < 2; ++j) {                          \
        acc[i + 4][j + 2] = MFMA(a[i][0], b23[j][0], acc[i + 4][j + 2]);       \
        acc[i + 4][j + 2] = MFMA(a[i][1], b23[j][1], acc[i + 4][j + 2]); }     \
    __builtin_amdgcn_s_setprio(0);                                             \
    /* ---- Ph4 (no ds_reads; a from Ph3, b01 from Ph1) ---- */                \
    if (S34) { STAGE_BH((CUR), 1, KOFF2); }                                    \
    __builtin_amdgcn_s_setprio(1);                                             \
    _Pragma("unroll") for (int i = 0; i < 4; ++i)                              \
      _Pragma("unroll") for (int j = 0; j < 2; ++j) {                          \
        acc[i + 4][j] = MFMA(a[i][0], b01[j][0], acc[i + 4][j]);               \
        acc[i + 4][j] = MFMA(a[i][1], b01[j][1], acc[i + 4][j]); }             \
    __builtin_amdgcn_s_setprio(0);                                             \
    ENDW; BARX();  /* END: publishes all of tile t+1 */                        \
  }

__global__ __launch_bounds__(512, 2) void gemm_bt_kernel(
    const unsigned short* __restrict__ xb, const unsigned short* __restrict__ wt,
    float* __restrict__ out) {
  __shared__ unsigned short sA[2 * BM * BK];  // 64 KB
  __shared__ unsigned short sB[2 * BN * BK];  // 64 KB

  const int t = threadIdx.x;      // 0..511
  const int lane = t & 63;
  const int w    = t >> 6;        // wave 0..7
  const int wr   = w >> 2;
  const int wc   = w & 3;
  const int quad = lane >> 4;
  const int lcol = lane & 15;

  // XCD-aware bijective block swizzle (NWG=512, %8==0)
  const int lid = blockIdx.y * GRID_X + blockIdx.x;
  const int swz = (lid & 7) * (NWG / 8) + (lid >> 3);
  const int n0 = (swz & (GRID_X - 1)) * BN;
  const int m0 = (swz / GRID_X) * BM;

  // ---- staging addresses ----
  const int g    = (lane & 7) ^ (lane >> 3);  // source chunk
  const int srow = w * 8 + (lane >> 3);
  const unsigned short* gA = xb + (size_t)(m0 + srow) * DIN + g * 8;
  const unsigned short* gB = wt + (size_t)(n0 + srow) * DIN + g * 8;

  // ---- fragment read offsets (shorts; row stride 64) ----
  const int xorv = lcol & 7;
  const int cp0  = (quad ^ xorv) * 8;
  const int cp1  = cp0 ^ 32;
  int aoff[8], boff[4];
  #pragma unroll
  for (int i = 0; i < 8; ++i)
    aoff[i] = ((i >> 2) * 128 + wr * 64 + (i & 3) * 16 + lcol) * 64;
  #pragma unroll
  for (int j = 0; j < 4; ++j)
    boff[j] = ((j >> 1) * 128 + wc * 32 + (j & 1) * 16 + lcol) * 64;

  f32x4 acc[8][4] = {};

  // ---- prologue: tile 0 complete + tile 1 all but Ah1 = 14 loads ----
  STAGE_BH(0, 0, 0);  STAGE_AH(0, 0, 0);  STAGE_BH(0, 1, 0);  STAGE_AH(0, 1, 0);
  STAGE_BH(1, 0, 64); STAGE_AH(1, 0, 64); STAGE_BH(1, 1, 64);
  VMW(6);             // retires tile 0's 8 loads; 6 of tile 1 in flight
  BARX();

  // tiles 0..61: fully steady
  #pragma unroll 2
  for (int tt = 0; tt < 62; ++tt) {
    const int cur = tt & 1;
    KTILE(cur, (tt + 1) * BK, (tt + 2) * BK, 1, 1, VMW(6));
  }
  // tile 62 (buf0): stage only Ah1(63); drain all 8 in flight at end
  KTILE(0, 63 * BK, 0, 1, 0, VMW(0));
  // tile 63 (buf1): no staging, no wait
  KTILE(1, 0, 0, 0, 0, ((void)0));

  // Epilogue: C/D layout col=lane&15, row=(lane>>4)*4+reg [m89/m91]
  #pragma unroll
  for (int i = 0; i < 8; ++i) {
    const int rb = m0 + (i >> 2) * 128 + wr * 64 + (i & 3) * 16 + quad * 4;
    #pragma unroll
    for (int j = 0; j < 4; ++j) {
      const int cb = n0 + (j >> 1) * 128 + wc * 32 + (j & 1) * 16 + lcol;
      #pragma unroll
      for (int r = 0; r < 4; ++r)
        out[(size_t)(rb + r) * DOUT + cb] = acc[i][j][r];
    }
  }
}

extern "C" void kernel_launch(void* const* d_in, const int* in_sizes, int n_in,
                              void* d_out, int out_size, void* d_ws, size_t ws_size,
                              hipStream_t stream) {
  const float* x    = (const float*)d_in[0];
  const float* W    = (const float*)d_in[1];
  const float* bias = (const float*)d_in[2];
  const float* A    = (const float*)d_in[3];
  const float* B    = (const float*)d_in[4];
  float* out      = (float*)d_out;
  float* bias_out = out + (size_t)SEQ * DOUT;

  unsigned short* xb = (unsigned short*)d_ws;
  unsigned short* wt = xb + (size_t)SEQ * DIN;

  prep_kernel<<<CAST_BLOCKS + WEFF_BLOCKS, 256, 0, stream>>>(
      x, xb, bias, bias_out, W, A, B, wt);
  gemm_bt_kernel<<<dim3(GRID_X, GRID_Y), 512, 0, stream>>>(xb, wt, out);
}